// Round 2
// baseline (889.412 us; speedup 1.0000x reference)
//
#include <hip/hip_runtime.h>
#include <stdint.h>

typedef unsigned short UST;
typedef __attribute__((ext_vector_type(8))) short    bf16x8;
typedef __attribute__((ext_vector_type(4))) float    f32x4;
typedef __attribute__((ext_vector_type(4))) float    float4_t;
typedef __attribute__((ext_vector_type(4))) UST      ushort4_t;
typedef __attribute__((ext_vector_type(8))) UST      ushort8_t;

__device__ __forceinline__ UST f2bf(float f) {
    union { float f; uint32_t u; } c; c.f = f;
    uint32_t u = c.u;
    u = (u + 0x7FFFu + ((u >> 16) & 1u)) >> 16;
    return (UST)u;
}
__device__ __forceinline__ float bf2f(UST h) {
    union { uint32_t u; float f; } c; c.u = ((uint32_t)h) << 16;
    return c.f;
}

__device__ __forceinline__ void async_copy16(const void* g, void* l) {
    __builtin_amdgcn_global_load_lds(
        (const __attribute__((address_space(1))) uint32_t*)g,
        (__attribute__((address_space(3))) uint32_t*)l, 16, 0, 0);
}

// ---------------------------------------------------------------------------
// GEMM: C[M,N] = A[M,K] * B[N,K]^T  (both inputs K-major, ld == K)
// TERMS: 1 = Ah*Bh ; 3 = Ah*Bh + Ah*Bl + Al*Bh  (split-precision)
// IN_FP32: 1 = A/B are fp32, split to hi/lo bf16 in-kernel during staging
//          0 = A/B are pre-split bf16 (hi in A/B, lo in Al/Bl), async LDS copy
// OUT_MODE: 0 = fp32 ; 1 = split bf16 (hi C0, lo C1) ; 2 = bf16 transposed
// Per-batch element strides sA/sB/sC, batch = blockIdx.z.
// ---------------------------------------------------------------------------
template <int TERMS, int IN_FP32, int OUT_MODE, bool HAS_BIAS>
__global__ __launch_bounds__(256, 2)
void gemm_bt(const void* __restrict__ Aptr, const UST* __restrict__ Al,
             const void* __restrict__ Bptr, const UST* __restrict__ Bl,
             const float* __restrict__ bias,
             void* __restrict__ C0, void* __restrict__ C1,
             int K, int ldc,
             long long sA, long long sB, long long sC) {
    __shared__ UST tAh[128 * 32];
    __shared__ UST tBh[128 * 32];
    __shared__ UST tAl[TERMS == 3 ? 128 * 32 : 4];
    __shared__ UST tBl[TERMS == 3 ? 128 * 32 : 4];

    const int bz = blockIdx.z;
    const int brow = blockIdx.y * 128;
    const int bcol = blockIdx.x * 128;

    const int t = threadIdx.x;
    const int wave = t >> 6, lane = t & 63;
    const int wr = (wave >> 1) * 64, wc = (wave & 1) * 64;
    const int lr = lane & 15, lg = lane >> 4;

    const int srow = t >> 2;        // 0..63
    const int scol = (t & 3) * 8;   // 0,8,16,24

    f32x4 acc[4][4];
#pragma unroll
    for (int m = 0; m < 4; m++)
#pragma unroll
        for (int n = 0; n < 4; n++) acc[m][n] = (f32x4){0.f, 0.f, 0.f, 0.f};

    const UST* Ah = (const UST*)Aptr + (IN_FP32 ? 0 : (long long)bz * sA);
    const UST* Bh = (const UST*)Bptr + (IN_FP32 ? 0 : (long long)bz * sB);
    const float* Af = (const float*)Aptr + (long long)bz * sA;
    const float* Bf = (const float*)Bptr + (long long)bz * sB;
    if constexpr (!IN_FP32) {
        if constexpr (TERMS == 3) {
            Al += (long long)bz * sA;
            Bl += (long long)bz * sB;
        }
    }

    for (int k0 = 0; k0 < K; k0 += 32) {
        if constexpr (IN_FP32) {
            // reg-stage fp32, split to hi/lo bf16, write LDS
#pragma unroll
            for (int h = 0; h < 2; h++) {
                const float* gA = Af + (size_t)(brow + srow + h * 64) * K + k0 + scol;
                float4_t v0 = *(const float4_t*)gA;
                float4_t v1 = *(const float4_t*)(gA + 4);
                ushort4_t h0, h1, l0, l1;
#pragma unroll
                for (int j = 0; j < 4; j++) {
                    h0[j] = f2bf(v0[j]); h1[j] = f2bf(v1[j]);
                    if (TERMS == 3) {
                        l0[j] = f2bf(v0[j] - bf2f(h0[j]));
                        l1[j] = f2bf(v1[j] - bf2f(h1[j]));
                    }
                }
                *(ushort4_t*)(tAh + h * 2048 + t * 8) = h0;
                *(ushort4_t*)(tAh + h * 2048 + t * 8 + 4) = h1;
                if (TERMS == 3) {
                    *(ushort4_t*)(tAl + h * 2048 + t * 8) = l0;
                    *(ushort4_t*)(tAl + h * 2048 + t * 8 + 4) = l1;
                }
            }
#pragma unroll
            for (int h = 0; h < 2; h++) {
                const float* gB = Bf + (size_t)(bcol + srow + h * 64) * K + k0 + scol;
                float4_t v0 = *(const float4_t*)gB;
                float4_t v1 = *(const float4_t*)(gB + 4);
                ushort4_t h0, h1, l0, l1;
#pragma unroll
                for (int j = 0; j < 4; j++) {
                    h0[j] = f2bf(v0[j]); h1[j] = f2bf(v1[j]);
                    if (TERMS == 3) {
                        l0[j] = f2bf(v0[j] - bf2f(h0[j]));
                        l1[j] = f2bf(v1[j] - bf2f(h1[j]));
                    }
                }
                *(ushort4_t*)(tBh + h * 2048 + t * 8) = h0;
                *(ushort4_t*)(tBh + h * 2048 + t * 8 + 4) = h1;
                if (TERMS == 3) {
                    *(ushort4_t*)(tBl + h * 2048 + t * 8) = l0;
                    *(ushort4_t*)(tBl + h * 2048 + t * 8 + 4) = l1;
                }
            }
        } else {
            const UST* gA = Ah + (size_t)(brow + srow) * (size_t)K + k0 + scol;
            async_copy16(gA, tAh + t * 8);
            async_copy16(gA + (size_t)64 * K, tAh + 2048 + t * 8);
            const UST* gB = Bh + (size_t)(bcol + srow) * (size_t)K + k0 + scol;
            async_copy16(gB, tBh + t * 8);
            async_copy16(gB + (size_t)64 * K, tBh + 2048 + t * 8);
            if constexpr (TERMS == 3) {
                const UST* gAl = Al + (size_t)(brow + srow) * (size_t)K + k0 + scol;
                async_copy16(gAl, tAl + t * 8);
                async_copy16(gAl + (size_t)64 * K, tAl + 2048 + t * 8);
                const UST* gBl = Bl + (size_t)(bcol + srow) * (size_t)K + k0 + scol;
                async_copy16(gBl, tBl + t * 8);
                async_copy16(gBl + (size_t)64 * K, tBl + 2048 + t * 8);
            }
        }
        __syncthreads();

        bf16x8 ah[4], bh[4];
#pragma unroll
        for (int m = 0; m < 4; m++)
            ah[m] = *(const bf16x8*)(tAh + (wr + m * 16 + lr) * 32 + lg * 8);
#pragma unroll
        for (int n = 0; n < 4; n++)
            bh[n] = *(const bf16x8*)(tBh + (wc + n * 16 + lr) * 32 + lg * 8);

        if constexpr (TERMS == 3) {
            bf16x8 al[4], bl[4];
#pragma unroll
            for (int m = 0; m < 4; m++)
                al[m] = *(const bf16x8*)(tAl + (wr + m * 16 + lr) * 32 + lg * 8);
#pragma unroll
            for (int n = 0; n < 4; n++)
                bl[n] = *(const bf16x8*)(tBl + (wc + n * 16 + lr) * 32 + lg * 8);
#pragma unroll
            for (int m = 0; m < 4; m++)
#pragma unroll
                for (int n = 0; n < 4; n++) {
                    acc[m][n] = __builtin_amdgcn_mfma_f32_16x16x32_bf16(ah[m], bh[n], acc[m][n], 0, 0, 0);
                    acc[m][n] = __builtin_amdgcn_mfma_f32_16x16x32_bf16(ah[m], bl[n], acc[m][n], 0, 0, 0);
                    acc[m][n] = __builtin_amdgcn_mfma_f32_16x16x32_bf16(al[m], bh[n], acc[m][n], 0, 0, 0);
                }
        } else {
#pragma unroll
            for (int m = 0; m < 4; m++)
#pragma unroll
                for (int n = 0; n < 4; n++)
                    acc[m][n] = __builtin_amdgcn_mfma_f32_16x16x32_bf16(ah[m], bh[n], acc[m][n], 0, 0, 0);
        }
        __syncthreads();
    }

    float bvv[4];
#pragma unroll
    for (int n = 0; n < 4; n++)
        bvv[n] = HAS_BIAS ? bias[bcol + wc + n * 16 + lr] : 0.0f;

#pragma unroll
    for (int m = 0; m < 4; m++) {
        const int row0 = brow + wr + m * 16 + lg * 4;
#pragma unroll
        for (int n = 0; n < 4; n++) {
            const int col = bcol + wc + n * 16 + lr;
            if constexpr (OUT_MODE == 0) {
                float* C = (float*)C0 + (long long)bz * sC;
#pragma unroll
                for (int j = 0; j < 4; j++)
                    C[(size_t)(row0 + j) * ldc + col] = acc[m][n][j] + bvv[n];
            } else if constexpr (OUT_MODE == 1) {
                UST* Hh = (UST*)C0 + (long long)bz * sC;
                UST* Ll = (UST*)C1 + (long long)bz * sC;
#pragma unroll
                for (int j = 0; j < 4; j++) {
                    float v = acc[m][n][j] + bvv[n];
                    UST h = f2bf(v);
                    Hh[(size_t)(row0 + j) * ldc + col] = h;
                    Ll[(size_t)(row0 + j) * ldc + col] = f2bf(v - bf2f(h));
                }
            } else {
                UST* V = (UST*)C0 + (long long)bz * sC;
                ushort4_t pk;
#pragma unroll
                for (int j = 0; j < 4; j++) pk[j] = f2bf(acc[m][n][j] + bvv[n]);
                *(ushort4_t*)(V + (size_t)col * ldc + row0) = pk;
            }
        }
    }
}

// ---------------------------------------------------------------------------
// row softmax over 2048 fp32 -> bf16 probs. One block (256 thr) per row.
// ---------------------------------------------------------------------------
__global__ __launch_bounds__(256)
void softmax_bf16(const float* __restrict__ S, UST* __restrict__ P) {
    const size_t row = blockIdx.x;
    const float* s = S + row * 2048;
    const int t = threadIdx.x;
    const int wave = t >> 6, lane = t & 63;

    float4_t v0 = *(const float4_t*)(s + t * 8);
    float4_t v1 = *(const float4_t*)(s + t * 8 + 4);
    float vv[8];
#pragma unroll
    for (int j = 0; j < 4; j++) { vv[j] = v0[j]; vv[4 + j] = v1[j]; }

    float m = vv[0];
#pragma unroll
    for (int j = 1; j < 8; j++) m = fmaxf(m, vv[j]);
#pragma unroll
    for (int off = 32; off; off >>= 1) m = fmaxf(m, __shfl_xor(m, off));

    __shared__ float red[16];
    if (lane == 0) red[wave] = m;
    __syncthreads();
    m = fmaxf(fmaxf(red[0], red[1]), fmaxf(red[2], red[3]));

    float e[8];
    float sum = 0.f;
#pragma unroll
    for (int j = 0; j < 8; j++) { e[j] = __expf(vv[j] - m); sum += e[j]; }
#pragma unroll
    for (int off = 32; off; off >>= 1) sum += __shfl_xor(sum, off);
    if (lane == 0) red[8 + wave] = sum;
    __syncthreads();
    sum = red[8] + red[9] + red[10] + red[11];

    float inv = 1.0f / sum;
    ushort8_t pk;
#pragma unroll
    for (int j = 0; j < 8; j++) pk[j] = f2bf(e[j] * inv);
    *(ushort8_t*)(P + row * 2048 + t * 8) = pk;
}

// ---------------------------------------------------------------------------
extern "C" void kernel_launch(void* const* d_in, const int* in_sizes, int n_in,
                              void* d_out, int out_size, void* d_ws, size_t ws_size,
                              hipStream_t stream) {
    (void)in_sizes; (void)n_in; (void)out_size;
    const float* x  = (const float*)d_in[0];
    const float* Wq = (const float*)d_in[1];
    const float* bq = (const float*)d_in[2];
    const float* Wk = (const float*)d_in[3];
    const float* bk = (const float*)d_in[4];
    const float* Wv = (const float*)d_in[5];
    const float* bv = (const float*)d_in[6];
    float* out = (float*)d_out;

    const int B = 8, S = 2048, H = 1024;
    const size_t BSH = (size_t)B * S * H;   // 16,777,216
    const long long sXH = (long long)S * H; // 2,097,152

    char* p = (char*)d_ws;
    UST* qh = (UST*)p; p += BSH * 2;
    UST* ql = (UST*)p; p += BSH * 2;
    UST* kh = (UST*)p; p += BSH * 2;
    UST* kl = (UST*)p; p += BSH * 2;
    UST* vt = (UST*)p; p += BSH * 2;   // [B][H][S]

    const size_t fixed = (size_t)(p - (char*)d_ws);          // 160 MiB
    const size_t perB = (size_t)S * S * 6;                    // 24 MiB: scores f32 + probs bf16
    const size_t avail = ws_size > fixed ? ws_size - fixed : 0;

    dim3 blk(256);
    dim3 gproj(H / 128, S / 128, B);   // (8,16,8)

    // 1. projections (fp32 inputs, in-kernel hi/lo split)
    gemm_bt<3, 1, 1, true><<<gproj, blk, 0, stream>>>(x, nullptr, Wq, nullptr, bq, qh, ql, H, H, sXH, 0, sXH);
    gemm_bt<3, 1, 1, true><<<gproj, blk, 0, stream>>>(x, nullptr, Wk, nullptr, bk, kh, kl, H, H, sXH, 0, sXH);
    gemm_bt<1, 1, 2, true><<<gproj, blk, 0, stream>>>(x, nullptr, Wv, nullptr, bv, vt, nullptr, H, S, sXH, 0, (long long)H * S);

    int g = (int)(avail / perB);
    if (g >= 1) {
        if (g > 8) g = 8;
        while (8 % g) g--;
        float* scores = (float*)p;
        UST* probs = (UST*)(p + (size_t)g * S * S * 4);

        for (int b0 = 0; b0 < B; b0 += g) {
            dim3 gsc(S / 128, S / 128, g);
            gemm_bt<3, 0, 0, false><<<gsc, blk, 0, stream>>>(
                qh + (size_t)b0 * S * H, ql + (size_t)b0 * S * H,
                kh + (size_t)b0 * S * H, kl + (size_t)b0 * S * H, nullptr,
                scores, nullptr, H, S, sXH, sXH, (long long)S * S);

            softmax_bf16<<<g * S, 256, 0, stream>>>(scores, probs);

            dim3 gpv(H / 128, S / 128, g);
            gemm_bt<1, 0, 0, false><<<gpv, blk, 0, stream>>>(
                probs, nullptr, vt + (size_t)b0 * H * S, nullptr, nullptr,
                out + (size_t)b0 * S * H, nullptr, S, H,
                (long long)S * S, (long long)H * S, sXH);
        }
    } else {
        // fallback: per-batch row-chunked scores (min footprint)
        int rows = (int)(avail / ((size_t)S * 6 * 128)) * 128;
        if (rows < 128) rows = 128;           // last resort
        if (rows > S) rows = S;
        float* scores = (float*)p;
        UST* probs = (UST*)(p + (size_t)rows * S * 4);

        for (int b = 0; b < B; b++) {
            for (int r0 = 0; r0 < S; r0 += rows) {
                int rc = S - r0 < rows ? S - r0 : rows;
                dim3 gsc(S / 128, rc / 128, 1);
                gemm_bt<3, 0, 0, false><<<gsc, blk, 0, stream>>>(
                    qh + (size_t)b * S * H + (size_t)r0 * H,
                    ql + (size_t)b * S * H + (size_t)r0 * H,
                    kh + (size_t)b * S * H, kl + (size_t)b * S * H, nullptr,
                    scores, nullptr, H, S, 0, 0, 0);

                softmax_bf16<<<rc, 256, 0, stream>>>(scores, probs);

                dim3 gpv(H / 128, rc / 128, 1);
                gemm_bt<1, 0, 0, false><<<gpv, blk, 0, stream>>>(
                    probs, nullptr, vt + (size_t)b * H * S, nullptr, nullptr,
                    out + (size_t)b * S * H + (size_t)r0 * H, nullptr, S, H,
                    0, 0, 0);
            }
        }
    }
}

// Round 3
// 659.361 us; speedup vs baseline: 1.3489x; 1.3489x over previous
//
#include <hip/hip_runtime.h>
#include <stdint.h>

typedef unsigned short UST;
typedef __attribute__((ext_vector_type(8))) short    bf16x8;
typedef __attribute__((ext_vector_type(4))) float    f32x4;
typedef __attribute__((ext_vector_type(4))) float    float4_t;
typedef __attribute__((ext_vector_type(4))) UST      ushort4_t;
typedef __attribute__((ext_vector_type(8))) UST      ushort8_t;

__device__ __forceinline__ UST f2bf(float f) {
    union { float f; uint32_t u; } c; c.f = f;
    uint32_t u = c.u;
    u = (u + 0x7FFFu + ((u >> 16) & 1u)) >> 16;
    return (UST)u;
}
__device__ __forceinline__ float bf2f(UST h) {
    union { uint32_t u; float f; } c; c.u = ((uint32_t)h) << 16;
    return c.f;
}

__device__ __forceinline__ void async_copy16(const void* g, void* l) {
    __builtin_amdgcn_global_load_lds(
        (const __attribute__((address_space(1))) uint32_t*)g,
        (__attribute__((address_space(3))) uint32_t*)l, 16, 0, 0);
}

// bijective XCD-aware block remap (nwg % 8 == 0 in all our grids)
__device__ __forceinline__ void xcd_remap(int& bx, int& by, int& bz) {
    const int gx = (int)gridDim.x, gy = (int)gridDim.y, gz = (int)gridDim.z;
    const int nwg = gx * gy * gz;
    if (nwg & 7) return;
    int flat = ((int)blockIdx.z * gy + (int)blockIdx.y) * gx + (int)blockIdx.x;
    const int q = nwg >> 3;
    int s = (flat & 7) * q + (flat >> 3);
    bx = s % gx; s /= gx;
    by = s % gy;
    bz = s / gy;
}

// ---------------------------------------------------------------------------
// split fp32 -> hi bf16 + lo bf16 (x = hi + lo + O(2^-16))
// ---------------------------------------------------------------------------
__global__ void split_kernel(const float* __restrict__ in, UST* __restrict__ hi,
                             UST* __restrict__ lo, int n4) {
    int i = blockIdx.x * blockDim.x + threadIdx.x;
    int stride = gridDim.x * blockDim.x;
    for (; i < n4; i += stride) {
        float4_t v = *(const float4_t*)(in + (size_t)i * 4);
        ushort4_t h, l;
#pragma unroll
        for (int j = 0; j < 4; j++) {
            float f = v[j];
            UST hh = f2bf(f);
            h[j] = hh;
            l[j] = f2bf(f - bf2f(hh));
        }
        *(ushort4_t*)(hi + (size_t)i * 4) = h;
        *(ushort4_t*)(lo + (size_t)i * 4) = l;
    }
}

__global__ void cvt_hi_kernel(const float* __restrict__ in, UST* __restrict__ hi, int n4) {
    int i = blockIdx.x * blockDim.x + threadIdx.x;
    int stride = gridDim.x * blockDim.x;
    for (; i < n4; i += stride) {
        float4_t v = *(const float4_t*)(in + (size_t)i * 4);
        ushort4_t h;
#pragma unroll
        for (int j = 0; j < 4; j++) h[j] = f2bf(v[j]);
        *(ushort4_t*)(hi + (size_t)i * 4) = h;
    }
}

// ---------------------------------------------------------------------------
// GEMM: C[M,N] = A[M,K] * B[N,K]^T  (both inputs K-major, ld == K)
// TERMS: 1 = Ah*Bh ; 3 = Ah*Bh + Ah*Bl + Al*Bh  (split-precision)
// IN_FP32: 1 = A/B fp32, split in-kernel (fallback); 0 = pre-split bf16 via
//          global_load_lds.
// OUT_MODE: 0 = fp32 ; 1 = split bf16 (hi C0, lo C1) ; 2 = bf16 transposed
//           (LDS-bounce, coalesced)
// LDS tiles are XOR-swizzled: logical (row, slot) lives at slot^((row>>1)&3).
// ---------------------------------------------------------------------------
template <int TERMS, int IN_FP32, int OUT_MODE, bool HAS_BIAS>
__global__ __launch_bounds__(256, 2)
void gemm_bt(const void* __restrict__ Aptr, const UST* __restrict__ Al,
             const void* __restrict__ Bptr, const UST* __restrict__ Bl,
             const float* __restrict__ bias,
             void* __restrict__ C0, void* __restrict__ C1,
             int K, int ldc,
             long long sA, long long sB, long long sC) {
    __shared__ UST lds[(TERMS == 3 || OUT_MODE == 2) ? 16384 : 8192];
    UST* tAh = lds;
    UST* tBh = lds + 4096;
    UST* tAl = lds + 8192;      // TERMS==3 only
    UST* tBl = lds + 12288;     // TERMS==3 only

    int bx = (int)blockIdx.x, by = (int)blockIdx.y, bz = (int)blockIdx.z;
    xcd_remap(bx, by, bz);
    const int brow = by * 128;
    const int bcol = bx * 128;

    const int t = threadIdx.x;
    const int wave = t >> 6, lane = t & 63;
    const int wr = (wave >> 1) * 64, wc = (wave & 1) * 64;
    const int lr = lane & 15, lg = lane >> 4;

    const int srow = t >> 2;                                  // 0..63
    const int slot = ((t & 3) ^ ((srow >> 1) & 3));           // swizzled col slot
    const int scol_sw = slot * 8;                             // UST units
    const int scol_lin = (t & 3) * 8;

    // swizzled ds_read offsets (UST units), loop-invariant
    int offA[4], offB[4];
#pragma unroll
    for (int m = 0; m < 4; m++) {
        int r = wr + m * 16 + lr;
        offA[m] = r * 32 + ((lg ^ ((r >> 1) & 3)) << 3);
    }
#pragma unroll
    for (int n = 0; n < 4; n++) {
        int r = wc + n * 16 + lr;
        offB[n] = r * 32 + ((lg ^ ((r >> 1) & 3)) << 3);
    }

    f32x4 acc[4][4];
#pragma unroll
    for (int m = 0; m < 4; m++)
#pragma unroll
        for (int n = 0; n < 4; n++) acc[m][n] = (f32x4){0.f, 0.f, 0.f, 0.f};

    const UST* Ah = (const UST*)Aptr + (IN_FP32 ? 0 : (long long)bz * sA);
    const UST* Bh = (const UST*)Bptr + (IN_FP32 ? 0 : (long long)bz * sB);
    const float* Af = (const float*)Aptr + (long long)bz * sA;
    const float* Bf = (const float*)Bptr + (long long)bz * sB;
    if constexpr (!IN_FP32) {
        if constexpr (TERMS == 3) {
            Al += (long long)bz * sA;
            Bl += (long long)bz * sB;
        }
    }

    for (int k0 = 0; k0 < K; k0 += 32) {
        if constexpr (IN_FP32) {
            // fallback: reg-stage fp32, split hi/lo, swizzled ds_write
#pragma unroll
            for (int h = 0; h < 2; h++) {
                const float* gA = Af + (size_t)(brow + srow + h * 64) * K + k0 + scol_lin;
                float4_t v0 = *(const float4_t*)gA;
                float4_t v1 = *(const float4_t*)(gA + 4);
                ushort4_t h0, h1, l0, l1;
#pragma unroll
                for (int j = 0; j < 4; j++) {
                    h0[j] = f2bf(v0[j]); h1[j] = f2bf(v1[j]);
                    if (TERMS == 3) {
                        l0[j] = f2bf(v0[j] - bf2f(h0[j]));
                        l1[j] = f2bf(v1[j] - bf2f(h1[j]));
                    }
                }
                UST* d = tAh + h * 2048 + srow * 32 + scol_sw;
                *(ushort4_t*)d = h0;
                *(ushort4_t*)(d + 4) = h1;
                if (TERMS == 3) {
                    UST* dl = tAl + h * 2048 + srow * 32 + scol_sw;
                    *(ushort4_t*)dl = l0;
                    *(ushort4_t*)(dl + 4) = l1;
                }
            }
#pragma unroll
            for (int h = 0; h < 2; h++) {
                const float* gB = Bf + (size_t)(bcol + srow + h * 64) * K + k0 + scol_lin;
                float4_t v0 = *(const float4_t*)gB;
                float4_t v1 = *(const float4_t*)(gB + 4);
                ushort4_t h0, h1, l0, l1;
#pragma unroll
                for (int j = 0; j < 4; j++) {
                    h0[j] = f2bf(v0[j]); h1[j] = f2bf(v1[j]);
                    if (TERMS == 3) {
                        l0[j] = f2bf(v0[j] - bf2f(h0[j]));
                        l1[j] = f2bf(v1[j] - bf2f(h1[j]));
                    }
                }
                UST* d = tBh + h * 2048 + srow * 32 + scol_sw;
                *(ushort4_t*)d = h0;
                *(ushort4_t*)(d + 4) = h1;
                if (TERMS == 3) {
                    UST* dl = tBl + h * 2048 + srow * 32 + scol_sw;
                    *(ushort4_t*)dl = l0;
                    *(ushort4_t*)(dl + 4) = l1;
                }
            }
        } else {
            // async path: LDS linear in t, global col pre-swizzled
            const UST* gA = Ah + (size_t)(brow + srow) * (size_t)K + k0 + scol_sw;
            async_copy16(gA, tAh + t * 8);
            async_copy16(gA + (size_t)64 * K, tAh + 2048 + t * 8);
            const UST* gB = Bh + (size_t)(bcol + srow) * (size_t)K + k0 + scol_sw;
            async_copy16(gB, tBh + t * 8);
            async_copy16(gB + (size_t)64 * K, tBh + 2048 + t * 8);
            if constexpr (TERMS == 3) {
                const UST* gAl = Al + (size_t)(brow + srow) * (size_t)K + k0 + scol_sw;
                async_copy16(gAl, tAl + t * 8);
                async_copy16(gAl + (size_t)64 * K, tAl + 2048 + t * 8);
                const UST* gBl = Bl + (size_t)(bcol + srow) * (size_t)K + k0 + scol_sw;
                async_copy16(gBl, tBl + t * 8);
                async_copy16(gBl + (size_t)64 * K, tBl + 2048 + t * 8);
            }
        }
        __syncthreads();

        bf16x8 ah[4], bh[4];
#pragma unroll
        for (int m = 0; m < 4; m++) ah[m] = *(const bf16x8*)(tAh + offA[m]);
#pragma unroll
        for (int n = 0; n < 4; n++) bh[n] = *(const bf16x8*)(tBh + offB[n]);

        if constexpr (TERMS == 3) {
            bf16x8 al[4], bl[4];
#pragma unroll
            for (int m = 0; m < 4; m++) al[m] = *(const bf16x8*)(tAl + offA[m]);
#pragma unroll
            for (int n = 0; n < 4; n++) bl[n] = *(const bf16x8*)(tBl + offB[n]);
#pragma unroll
            for (int m = 0; m < 4; m++)
#pragma unroll
                for (int n = 0; n < 4; n++) {
                    acc[m][n] = __builtin_amdgcn_mfma_f32_16x16x32_bf16(ah[m], bh[n], acc[m][n], 0, 0, 0);
                    acc[m][n] = __builtin_amdgcn_mfma_f32_16x16x32_bf16(ah[m], bl[n], acc[m][n], 0, 0, 0);
                    acc[m][n] = __builtin_amdgcn_mfma_f32_16x16x32_bf16(al[m], bh[n], acc[m][n], 0, 0, 0);
                }
        } else {
#pragma unroll
            for (int m = 0; m < 4; m++)
#pragma unroll
                for (int n = 0; n < 4; n++)
                    acc[m][n] = __builtin_amdgcn_mfma_f32_16x16x32_bf16(ah[m], bh[n], acc[m][n], 0, 0, 0);
        }
        __syncthreads();
    }

    float bvv[4];
#pragma unroll
    for (int n = 0; n < 4; n++)
        bvv[n] = HAS_BIAS ? bias[bcol + wc + n * 16 + lr] : 0.0f;

    if constexpr (OUT_MODE == 2) {
        // transposed bf16 out via LDS bounce (coalesced global stores)
#pragma unroll
        for (int m = 0; m < 4; m++) {
            const int r0 = wr + m * 16 + lg * 4;
#pragma unroll
            for (int n = 0; n < 4; n++) {
                const int c = wc + n * 16 + lr;
                ushort4_t pk;
#pragma unroll
                for (int j = 0; j < 4; j++) pk[j] = f2bf(acc[m][n][j] + bvv[n]);
                *(ushort4_t*)(lds + c * 128 + r0) = pk;
            }
        }
        __syncthreads();
        UST* V = (UST*)C0 + (long long)bz * sC;
        const int hl = t >> 1, soff = (t & 1) * 64;
        const UST* src = lds + hl * 128 + soff;
        UST* dst = V + (size_t)(bcol + hl) * ldc + brow + soff;
#pragma unroll
        for (int i = 0; i < 8; i++)
            *(ushort8_t*)(dst + i * 8) = *(const ushort8_t*)(src + i * 8);
        return;
    }

#pragma unroll
    for (int m = 0; m < 4; m++) {
        const int row0 = brow + wr + m * 16 + lg * 4;
#pragma unroll
        for (int n = 0; n < 4; n++) {
            const int col = bcol + wc + n * 16 + lr;
            if constexpr (OUT_MODE == 0) {
                float* C = (float*)C0 + (long long)bz * sC;
#pragma unroll
                for (int j = 0; j < 4; j++)
                    C[(size_t)(row0 + j) * ldc + col] = acc[m][n][j] + bvv[n];
            } else if constexpr (OUT_MODE == 1) {
                UST* Hh = (UST*)C0 + (long long)bz * sC;
                UST* Ll = (UST*)C1 + (long long)bz * sC;
#pragma unroll
                for (int j = 0; j < 4; j++) {
                    float v = acc[m][n][j] + bvv[n];
                    UST h = f2bf(v);
                    Hh[(size_t)(row0 + j) * ldc + col] = h;
                    Ll[(size_t)(row0 + j) * ldc + col] = f2bf(v - bf2f(h));
                }
            }
        }
    }
}

// ---------------------------------------------------------------------------
// row softmax over 2048 fp32 -> bf16 probs. One block (256 thr) per row.
// ---------------------------------------------------------------------------
__global__ __launch_bounds__(256)
void softmax_bf16(const float* __restrict__ S, UST* __restrict__ P) {
    const size_t row = blockIdx.x;
    const float* s = S + row * 2048;
    const int t = threadIdx.x;
    const int wave = t >> 6, lane = t & 63;

    float4_t v0 = *(const float4_t*)(s + t * 8);
    float4_t v1 = *(const float4_t*)(s + t * 8 + 4);
    float vv[8];
#pragma unroll
    for (int j = 0; j < 4; j++) { vv[j] = v0[j]; vv[4 + j] = v1[j]; }

    float m = vv[0];
#pragma unroll
    for (int j = 1; j < 8; j++) m = fmaxf(m, vv[j]);
#pragma unroll
    for (int off = 32; off; off >>= 1) m = fmaxf(m, __shfl_xor(m, off));

    __shared__ float red[16];
    if (lane == 0) red[wave] = m;
    __syncthreads();
    m = fmaxf(fmaxf(red[0], red[1]), fmaxf(red[2], red[3]));

    float e[8];
    float sum = 0.f;
#pragma unroll
    for (int j = 0; j < 8; j++) { e[j] = __expf(vv[j] - m); sum += e[j]; }
#pragma unroll
    for (int off = 32; off; off >>= 1) sum += __shfl_xor(sum, off);
    if (lane == 0) red[8 + wave] = sum;
    __syncthreads();
    sum = red[8] + red[9] + red[10] + red[11];

    float inv = 1.0f / sum;
    ushort8_t pk;
#pragma unroll
    for (int j = 0; j < 8; j++) pk[j] = f2bf(e[j] * inv);
    *(ushort8_t*)(P + row * 2048 + t * 8) = pk;
}

// ---------------------------------------------------------------------------
extern "C" void kernel_launch(void* const* d_in, const int* in_sizes, int n_in,
                              void* d_out, int out_size, void* d_ws, size_t ws_size,
                              hipStream_t stream) {
    (void)in_sizes; (void)n_in; (void)out_size;
    const float* x  = (const float*)d_in[0];
    const float* Wq = (const float*)d_in[1];
    const float* bq = (const float*)d_in[2];
    const float* Wk = (const float*)d_in[3];
    const float* bk = (const float*)d_in[4];
    const float* Wv = (const float*)d_in[5];
    const float* bv = (const float*)d_in[6];
    float* out = (float*)d_out;

    const int B = 8, S = 2048, H = 1024;
    const size_t BSH = (size_t)B * S * H;   // 16,777,216
    const long long sXH = (long long)S * H; // 2,097,152

    char* p = (char*)d_ws;
    UST* qh = (UST*)p; p += BSH * 2;
    UST* ql = (UST*)p; p += BSH * 2;
    UST* kh = (UST*)p; p += BSH * 2;
    UST* kl = (UST*)p; p += BSH * 2;
    UST* vt = (UST*)p; p += BSH * 2;   // [B][H][S]

    const size_t fixed = (size_t)(p - (char*)d_ws);           // 160 MiB
    const size_t perB = (size_t)S * S * 6;                    // 24 MiB/batch
    const size_t avail = ws_size > fixed ? ws_size - fixed : 0;

    const size_t HH = (size_t)H * H;
    const size_t splitBytes = BSH * 2 * 2 + HH * 2 * 5;       // 74 MiB

    dim3 blk(256);
    dim3 gproj(H / 128, S / 128, B);   // (8,16,8)

    if (avail >= splitBytes) {
        // tail region: split buffers now, scores/probs later (aliased)
        char* q = p;
        UST* xh  = (UST*)q; q += BSH * 2;
        UST* xl  = (UST*)q; q += BSH * 2;
        UST* wqh = (UST*)q; q += HH * 2;
        UST* wql = (UST*)q; q += HH * 2;
        UST* wkh = (UST*)q; q += HH * 2;
        UST* wkl = (UST*)q; q += HH * 2;
        UST* wvh = (UST*)q; q += HH * 2;

        split_kernel<<<2048, blk, 0, stream>>>(x, xh, xl, (int)(BSH / 4));
        split_kernel<<<256, blk, 0, stream>>>(Wq, wqh, wql, (int)(HH / 4));
        split_kernel<<<256, blk, 0, stream>>>(Wk, wkh, wkl, (int)(HH / 4));
        cvt_hi_kernel<<<256, blk, 0, stream>>>(Wv, wvh, (int)(HH / 4));

        gemm_bt<3, 0, 1, true><<<gproj, blk, 0, stream>>>(xh, xl, wqh, wql, bq, qh, ql, H, H, sXH, 0, sXH);
        gemm_bt<3, 0, 1, true><<<gproj, blk, 0, stream>>>(xh, xl, wkh, wkl, bk, kh, kl, H, H, sXH, 0, sXH);
        gemm_bt<1, 0, 2, true><<<gproj, blk, 0, stream>>>(xh, nullptr, wvh, nullptr, bv, vt, nullptr, H, S, sXH, 0, (long long)H * S);

        int g = (int)(avail / perB);
        if (g > 8) g = 8;
        if (g < 1) g = 1;
        while (8 % g) g--;
        float* scores = (float*)p;            // aliases split buffers (dead now)
        UST* probs = (UST*)(p + (size_t)g * S * S * 4);

        for (int b0 = 0; b0 < B; b0 += g) {
            dim3 gsc(S / 128, S / 128, g);
            gemm_bt<3, 0, 0, false><<<gsc, blk, 0, stream>>>(
                qh + (size_t)b0 * S * H, ql + (size_t)b0 * S * H,
                kh + (size_t)b0 * S * H, kl + (size_t)b0 * S * H, nullptr,
                scores, nullptr, H, S, sXH, sXH, (long long)S * S);

            softmax_bf16<<<g * S, blk, 0, stream>>>(scores, probs);

            dim3 gpv(H / 128, S / 128, g);
            gemm_bt<1, 0, 0, false><<<gpv, blk, 0, stream>>>(
                probs, nullptr, vt + (size_t)b0 * H * S, nullptr, nullptr,
                out + (size_t)b0 * S * H, nullptr, S, H,
                (long long)S * S, (long long)H * S, sXH);
        }
    } else {
        // tight-workspace fallback: in-kernel fp32 split + row-chunked scores
        gemm_bt<3, 1, 1, true><<<gproj, blk, 0, stream>>>(x, nullptr, Wq, nullptr, bq, qh, ql, H, H, sXH, 0, sXH);
        gemm_bt<3, 1, 1, true><<<gproj, blk, 0, stream>>>(x, nullptr, Wk, nullptr, bk, kh, kl, H, H, sXH, 0, sXH);
        gemm_bt<1, 1, 2, true><<<gproj, blk, 0, stream>>>(x, nullptr, Wv, nullptr, bv, vt, nullptr, H, S, sXH, 0, (long long)H * S);

        int rows = (int)(avail / ((size_t)S * 6 * 128)) * 128;
        if (rows < 128) rows = 128;
        if (rows > S) rows = S;
        float* scores = (float*)p;
        UST* probs = (UST*)(p + (size_t)rows * S * 4);

        for (int b = 0; b < B; b++) {
            for (int r0 = 0; r0 < S; r0 += rows) {
                int rc = S - r0 < rows ? S - r0 : rows;
                dim3 gsc(S / 128, rc / 128, 1);
                gemm_bt<3, 0, 0, false><<<gsc, blk, 0, stream>>>(
                    qh + (size_t)b * S * H + (size_t)r0 * H,
                    ql + (size_t)b * S * H + (size_t)r0 * H,
                    kh + (size_t)b * S * H, kl + (size_t)b * S * H, nullptr,
                    scores, nullptr, H, S, 0, 0, 0);

                softmax_bf16<<<rc, blk, 0, stream>>>(scores, probs);

                dim3 gpv(H / 128, rc / 128, 1);
                gemm_bt<1, 0, 0, false><<<gpv, blk, 0, stream>>>(
                    probs, nullptr, vt + (size_t)b * H * S, nullptr, nullptr,
                    out + (size_t)b * S * H + (size_t)r0 * H, nullptr, S, H,
                    0, 0, 0);
            }
        }
    }
}

// Round 4
// 600.210 us; speedup vs baseline: 1.4818x; 1.0986x over previous
//
#include <hip/hip_runtime.h>
#include <stdint.h>

typedef unsigned short UST;
typedef __attribute__((ext_vector_type(8))) short    bf16x8;
typedef __attribute__((ext_vector_type(4))) float    f32x4;
typedef __attribute__((ext_vector_type(4))) float    float4_t;
typedef __attribute__((ext_vector_type(4))) UST      ushort4_t;
typedef __attribute__((ext_vector_type(8))) UST      ushort8_t;

__device__ __forceinline__ UST f2bf(float f) {
    union { float f; uint32_t u; } c; c.f = f;
    uint32_t u = c.u;
    u = (u + 0x7FFFu + ((u >> 16) & 1u)) >> 16;
    return (UST)u;
}
__device__ __forceinline__ float bf2f(UST h) {
    union { uint32_t u; float f; } c; c.u = ((uint32_t)h) << 16;
    return c.f;
}

__device__ __forceinline__ void async_copy16(const void* g, void* l) {
    __builtin_amdgcn_global_load_lds(
        (const __attribute__((address_space(1))) uint32_t*)g,
        (__attribute__((address_space(3))) uint32_t*)l, 16, 0, 0);
}

// bijective XCD-aware block remap (nwg % 8 == 0 in all our grids)
__device__ __forceinline__ void xcd_remap(int& bx, int& by, int& bz) {
    const int gx = (int)gridDim.x, gy = (int)gridDim.y, gz = (int)gridDim.z;
    const int nwg = gx * gy * gz;
    if (nwg & 7) return;
    int flat = ((int)blockIdx.z * gy + (int)blockIdx.y) * gx + (int)blockIdx.x;
    const int q = nwg >> 3;
    int s = (flat & 7) * q + (flat >> 3);
    bx = s % gx; s /= gx;
    by = s % gy;
    bz = s / gy;
}

// ---------------------------------------------------------------------------
// split fp32 -> hi bf16 + lo bf16 (x = hi + lo + O(2^-16))
// ---------------------------------------------------------------------------
__global__ void split_kernel(const float* __restrict__ in, UST* __restrict__ hi,
                             UST* __restrict__ lo, int n4) {
    int i = blockIdx.x * blockDim.x + threadIdx.x;
    int stride = gridDim.x * blockDim.x;
    for (; i < n4; i += stride) {
        float4_t v = *(const float4_t*)(in + (size_t)i * 4);
        ushort4_t h, l;
#pragma unroll
        for (int j = 0; j < 4; j++) {
            float f = v[j];
            UST hh = f2bf(f);
            h[j] = hh;
            l[j] = f2bf(f - bf2f(hh));
        }
        *(ushort4_t*)(hi + (size_t)i * 4) = h;
        *(ushort4_t*)(lo + (size_t)i * 4) = l;
    }
}

__global__ void cvt_hi_kernel(const float* __restrict__ in, UST* __restrict__ hi, int n4) {
    int i = blockIdx.x * blockDim.x + threadIdx.x;
    int stride = gridDim.x * blockDim.x;
    for (; i < n4; i += stride) {
        float4_t v = *(const float4_t*)(in + (size_t)i * 4);
        ushort4_t h;
#pragma unroll
        for (int j = 0; j < 4; j++) h[j] = f2bf(v[j]);
        *(ushort4_t*)(hi + (size_t)i * 4) = h;
    }
}

// ---------------------------------------------------------------------------
// GEMM: C[M,N] = A[M,K] * B[N,K]^T  (both inputs K-major, ld == K)
// TERMS: 1 = Ah*Bh ; 3 = Ah*Bh + Ah*Bl + Al*Bh  (split-precision)
// IN_FP32: 1 = A/B fp32, split in-kernel (fallback, single-buffered);
//          0 = pre-split bf16 via global_load_lds, double-buffered prefetch.
// OUT_MODE: 0 = fp32 ; 1 = split bf16 (hi C0, lo C1) ; 2 = bf16 transposed
//           (LDS-bounce, coalesced)
// LDS tiles XOR-swizzled: logical (row, slot) lives at slot^((row>>1)&3).
// Double-buffer K-loop: issue tile t+1 loads BEFORE computing tile t; the
// single __syncthreads per step drains vmcnt after ~960 cyc of compute.
// ---------------------------------------------------------------------------
template <int TERMS, int IN_FP32, int OUT_MODE, bool HAS_BIAS>
__global__ __launch_bounds__(256, 2)
void gemm_bt(const void* __restrict__ Aptr, const UST* __restrict__ Al,
             const void* __restrict__ Bptr, const UST* __restrict__ Bl,
             const float* __restrict__ bias,
             void* __restrict__ C0, void* __restrict__ C1,
             int K, int ldc,
             long long sA, long long sB, long long sC) {
    constexpr int HALF = (TERMS == 3) ? 16384 : 8192;   // UST units per buffer
    constexpr int LREQ = IN_FP32 ? 16384 : 2 * HALF;
    constexpr int LTOT = LREQ > 16384 ? LREQ : 16384;   // epilogue bounce needs 16384
    __shared__ UST lds[LTOT];

    int bx = (int)blockIdx.x, by = (int)blockIdx.y, bz = (int)blockIdx.z;
    xcd_remap(bx, by, bz);
    const int brow = by * 128;
    const int bcol = bx * 128;

    const int t = threadIdx.x;
    const int wave = t >> 6, lane = t & 63;
    const int wr = (wave >> 1) * 64, wc = (wave & 1) * 64;
    const int lr = lane & 15, lg = lane >> 4;

    const int srow = t >> 2;                                  // 0..63
    const int slot = ((t & 3) ^ ((srow >> 1) & 3));           // swizzled col slot
    const int scol_sw = slot * 8;                             // UST units
    const int scol_lin = (t & 3) * 8;

    // swizzled ds_read offsets (UST units, relative to each tile base)
    int offA[4], offB[4];
#pragma unroll
    for (int m = 0; m < 4; m++) {
        int r = wr + m * 16 + lr;
        offA[m] = r * 32 + ((lg ^ ((r >> 1) & 3)) << 3);
    }
#pragma unroll
    for (int n = 0; n < 4; n++) {
        int r = wc + n * 16 + lr;
        offB[n] = r * 32 + ((lg ^ ((r >> 1) & 3)) << 3);
    }

    f32x4 acc[4][4];
#pragma unroll
    for (int m = 0; m < 4; m++)
#pragma unroll
        for (int n = 0; n < 4; n++) acc[m][n] = (f32x4){0.f, 0.f, 0.f, 0.f};

    const UST* Ah = (const UST*)Aptr + (IN_FP32 ? 0 : (long long)bz * sA);
    const UST* Bh = (const UST*)Bptr + (IN_FP32 ? 0 : (long long)bz * sB);
    const float* Af = (const float*)Aptr + (long long)bz * sA;
    const float* Bf = (const float*)Bptr + (long long)bz * sB;
    if constexpr (!IN_FP32) {
        if constexpr (TERMS == 3) {
            Al += (long long)bz * sA;
            Bl += (long long)bz * sB;
        }
    }

    if constexpr (!IN_FP32) {
        auto stage = [&](UST* dst, int k0) {
            const UST* gA = Ah + (size_t)(brow + srow) * (size_t)K + k0 + scol_sw;
            async_copy16(gA, dst + t * 8);
            async_copy16(gA + (size_t)64 * K, dst + 2048 + t * 8);
            const UST* gB = Bh + (size_t)(bcol + srow) * (size_t)K + k0 + scol_sw;
            async_copy16(gB, dst + 4096 + t * 8);
            async_copy16(gB + (size_t)64 * K, dst + 6144 + t * 8);
            if constexpr (TERMS == 3) {
                const UST* gAl = Al + (size_t)(brow + srow) * (size_t)K + k0 + scol_sw;
                async_copy16(gAl, dst + 8192 + t * 8);
                async_copy16(gAl + (size_t)64 * K, dst + 10240 + t * 8);
                const UST* gBl = Bl + (size_t)(bcol + srow) * (size_t)K + k0 + scol_sw;
                async_copy16(gBl, dst + 12288 + t * 8);
                async_copy16(gBl + (size_t)64 * K, dst + 14336 + t * 8);
            }
        };

        stage(lds, 0);
        __syncthreads();                 // drains vmcnt(0), releases tile 0
        int cur = 0;
        for (int k0 = 0; k0 < K; k0 += 32) {
            UST* buf = lds + cur * HALF;
            if (k0 + 32 < K) stage(lds + (cur ^ 1) * HALF, k0 + 32);

            bf16x8 ah[4], bh[4];
#pragma unroll
            for (int m = 0; m < 4; m++) ah[m] = *(const bf16x8*)(buf + offA[m]);
#pragma unroll
            for (int n = 0; n < 4; n++) bh[n] = *(const bf16x8*)(buf + 4096 + offB[n]);

            if constexpr (TERMS == 3) {
                bf16x8 al[4], bl[4];
#pragma unroll
                for (int m = 0; m < 4; m++) al[m] = *(const bf16x8*)(buf + 8192 + offA[m]);
#pragma unroll
                for (int n = 0; n < 4; n++) bl[n] = *(const bf16x8*)(buf + 12288 + offB[n]);
#pragma unroll
                for (int m = 0; m < 4; m++)
#pragma unroll
                    for (int n = 0; n < 4; n++) {
                        acc[m][n] = __builtin_amdgcn_mfma_f32_16x16x32_bf16(ah[m], bh[n], acc[m][n], 0, 0, 0);
                        acc[m][n] = __builtin_amdgcn_mfma_f32_16x16x32_bf16(ah[m], bl[n], acc[m][n], 0, 0, 0);
                        acc[m][n] = __builtin_amdgcn_mfma_f32_16x16x32_bf16(al[m], bh[n], acc[m][n], 0, 0, 0);
                    }
            } else {
#pragma unroll
                for (int m = 0; m < 4; m++)
#pragma unroll
                    for (int n = 0; n < 4; n++)
                        acc[m][n] = __builtin_amdgcn_mfma_f32_16x16x32_bf16(ah[m], bh[n], acc[m][n], 0, 0, 0);
            }
            __syncthreads();             // drains t+1 loads after compute
            cur ^= 1;
        }
    } else {
        // fallback: reg-stage fp32, split hi/lo, single-buffered
        UST* tAh = lds;
        UST* tBh = lds + 4096;
        UST* tAl = lds + 8192;
        UST* tBl = lds + 12288;
        for (int k0 = 0; k0 < K; k0 += 32) {
#pragma unroll
            for (int h = 0; h < 2; h++) {
                const float* gA = Af + (size_t)(brow + srow + h * 64) * K + k0 + scol_lin;
                float4_t v0 = *(const float4_t*)gA;
                float4_t v1 = *(const float4_t*)(gA + 4);
                ushort4_t h0, h1, l0, l1;
#pragma unroll
                for (int j = 0; j < 4; j++) {
                    h0[j] = f2bf(v0[j]); h1[j] = f2bf(v1[j]);
                    if (TERMS == 3) {
                        l0[j] = f2bf(v0[j] - bf2f(h0[j]));
                        l1[j] = f2bf(v1[j] - bf2f(h1[j]));
                    }
                }
                UST* d = tAh + h * 2048 + srow * 32 + scol_sw;
                *(ushort4_t*)d = h0;
                *(ushort4_t*)(d + 4) = h1;
                if (TERMS == 3) {
                    UST* dl = tAl + h * 2048 + srow * 32 + scol_sw;
                    *(ushort4_t*)dl = l0;
                    *(ushort4_t*)(dl + 4) = l1;
                }
            }
#pragma unroll
            for (int h = 0; h < 2; h++) {
                const float* gB = Bf + (size_t)(bcol + srow + h * 64) * K + k0 + scol_lin;
                float4_t v0 = *(const float4_t*)gB;
                float4_t v1 = *(const float4_t*)(gB + 4);
                ushort4_t h0, h1, l0, l1;
#pragma unroll
                for (int j = 0; j < 4; j++) {
                    h0[j] = f2bf(v0[j]); h1[j] = f2bf(v1[j]);
                    if (TERMS == 3) {
                        l0[j] = f2bf(v0[j] - bf2f(h0[j]));
                        l1[j] = f2bf(v1[j] - bf2f(h1[j]));
                    }
                }
                UST* d = tBh + h * 2048 + srow * 32 + scol_sw;
                *(ushort4_t*)d = h0;
                *(ushort4_t*)(d + 4) = h1;
                if (TERMS == 3) {
                    UST* dl = tBl + h * 2048 + srow * 32 + scol_sw;
                    *(ushort4_t*)dl = l0;
                    *(ushort4_t*)(dl + 4) = l1;
                }
            }
            __syncthreads();

            bf16x8 ah[4], bh[4];
#pragma unroll
            for (int m = 0; m < 4; m++) ah[m] = *(const bf16x8*)(tAh + offA[m]);
#pragma unroll
            for (int n = 0; n < 4; n++) bh[n] = *(const bf16x8*)(tBh + offB[n]);

            if constexpr (TERMS == 3) {
                bf16x8 al[4], bl[4];
#pragma unroll
                for (int m = 0; m < 4; m++) al[m] = *(const bf16x8*)(tAl + offA[m]);
#pragma unroll
                for (int n = 0; n < 4; n++) bl[n] = *(const bf16x8*)(tBl + offB[n]);
#pragma unroll
                for (int m = 0; m < 4; m++)
#pragma unroll
                    for (int n = 0; n < 4; n++) {
                        acc[m][n] = __builtin_amdgcn_mfma_f32_16x16x32_bf16(ah[m], bh[n], acc[m][n], 0, 0, 0);
                        acc[m][n] = __builtin_amdgcn_mfma_f32_16x16x32_bf16(ah[m], bl[n], acc[m][n], 0, 0, 0);
                        acc[m][n] = __builtin_amdgcn_mfma_f32_16x16x32_bf16(al[m], bh[n], acc[m][n], 0, 0, 0);
                    }
            } else {
#pragma unroll
                for (int m = 0; m < 4; m++)
#pragma unroll
                    for (int n = 0; n < 4; n++)
                        acc[m][n] = __builtin_amdgcn_mfma_f32_16x16x32_bf16(ah[m], bh[n], acc[m][n], 0, 0, 0);
            }
            __syncthreads();
        }
    }

    float bvv[4];
#pragma unroll
    for (int n = 0; n < 4; n++)
        bvv[n] = HAS_BIAS ? bias[bcol + wc + n * 16 + lr] : 0.0f;

    if constexpr (OUT_MODE == 2) {
        // transposed bf16 out via LDS bounce (coalesced global stores)
#pragma unroll
        for (int m = 0; m < 4; m++) {
            const int r0 = wr + m * 16 + lg * 4;
#pragma unroll
            for (int n = 0; n < 4; n++) {
                const int c = wc + n * 16 + lr;
                ushort4_t pk;
#pragma unroll
                for (int j = 0; j < 4; j++) pk[j] = f2bf(acc[m][n][j] + bvv[n]);
                *(ushort4_t*)(lds + c * 128 + r0) = pk;
            }
        }
        __syncthreads();
        UST* V = (UST*)C0 + (long long)bz * sC;
        const int hl = t >> 1, soff = (t & 1) * 64;
        const UST* src = lds + hl * 128 + soff;
        UST* dst = V + (size_t)(bcol + hl) * ldc + brow + soff;
#pragma unroll
        for (int i = 0; i < 8; i++)
            *(ushort8_t*)(dst + i * 8) = *(const ushort8_t*)(src + i * 8);
        return;
    }

#pragma unroll
    for (int m = 0; m < 4; m++) {
        const int row0 = brow + wr + m * 16 + lg * 4;
#pragma unroll
        for (int n = 0; n < 4; n++) {
            const int col = bcol + wc + n * 16 + lr;
            if constexpr (OUT_MODE == 0) {
                float* C = (float*)C0 + (long long)bz * sC;
#pragma unroll
                for (int j = 0; j < 4; j++)
                    C[(size_t)(row0 + j) * ldc + col] = acc[m][n][j] + bvv[n];
            } else if constexpr (OUT_MODE == 1) {
                UST* Hh = (UST*)C0 + (long long)bz * sC;
                UST* Ll = (UST*)C1 + (long long)bz * sC;
#pragma unroll
                for (int j = 0; j < 4; j++) {
                    float v = acc[m][n][j] + bvv[n];
                    UST h = f2bf(v);
                    Hh[(size_t)(row0 + j) * ldc + col] = h;
                    Ll[(size_t)(row0 + j) * ldc + col] = f2bf(v - bf2f(h));
                }
            }
        }
    }
}

// ---------------------------------------------------------------------------
// row softmax over 2048 fp32 -> bf16 probs. One block (256 thr) per row.
// ---------------------------------------------------------------------------
__global__ __launch_bounds__(256)
void softmax_bf16(const float* __restrict__ S, UST* __restrict__ P) {
    const size_t row = blockIdx.x;
    const float* s = S + row * 2048;
    const int t = threadIdx.x;
    const int wave = t >> 6, lane = t & 63;

    float4_t v0 = *(const float4_t*)(s + t * 8);
    float4_t v1 = *(const float4_t*)(s + t * 8 + 4);
    float vv[8];
#pragma unroll
    for (int j = 0; j < 4; j++) { vv[j] = v0[j]; vv[4 + j] = v1[j]; }

    float m = vv[0];
#pragma unroll
    for (int j = 1; j < 8; j++) m = fmaxf(m, vv[j]);
#pragma unroll
    for (int off = 32; off; off >>= 1) m = fmaxf(m, __shfl_xor(m, off));

    __shared__ float red[16];
    if (lane == 0) red[wave] = m;
    __syncthreads();
    m = fmaxf(fmaxf(red[0], red[1]), fmaxf(red[2], red[3]));

    float e[8];
    float sum = 0.f;
#pragma unroll
    for (int j = 0; j < 8; j++) { e[j] = __expf(vv[j] - m); sum += e[j]; }
#pragma unroll
    for (int off = 32; off; off >>= 1) sum += __shfl_xor(sum, off);
    if (lane == 0) red[8 + wave] = sum;
    __syncthreads();
    sum = red[8] + red[9] + red[10] + red[11];

    float inv = 1.0f / sum;
    ushort8_t pk;
#pragma unroll
    for (int j = 0; j < 8; j++) pk[j] = f2bf(e[j] * inv);
    *(ushort8_t*)(P + row * 2048 + t * 8) = pk;
}

// ---------------------------------------------------------------------------
extern "C" void kernel_launch(void* const* d_in, const int* in_sizes, int n_in,
                              void* d_out, int out_size, void* d_ws, size_t ws_size,
                              hipStream_t stream) {
    (void)in_sizes; (void)n_in; (void)out_size;
    const float* x  = (const float*)d_in[0];
    const float* Wq = (const float*)d_in[1];
    const float* bq = (const float*)d_in[2];
    const float* Wk = (const float*)d_in[3];
    const float* bk = (const float*)d_in[4];
    const float* Wv = (const float*)d_in[5];
    const float* bv = (const float*)d_in[6];
    float* out = (float*)d_out;

    const int B = 8, S = 2048, H = 1024;
    const size_t BSH = (size_t)B * S * H;   // 16,777,216
    const long long sXH = (long long)S * H; // 2,097,152

    char* p = (char*)d_ws;
    UST* qh = (UST*)p; p += BSH * 2;
    UST* ql = (UST*)p; p += BSH * 2;
    UST* kh = (UST*)p; p += BSH * 2;
    UST* kl = (UST*)p; p += BSH * 2;
    UST* vt = (UST*)p; p += BSH * 2;   // [B][H][S]

    const size_t fixed = (size_t)(p - (char*)d_ws);           // 160 MiB
    const size_t perB = (size_t)S * S * 6;                    // 24 MiB/batch
    const size_t avail = ws_size > fixed ? ws_size - fixed : 0;

    const size_t HH = (size_t)H * H;
    const size_t splitBytes = BSH * 2 * 2 + HH * 2 * 5;       // 74 MiB

    dim3 blk(256);
    dim3 gproj(H / 128, S / 128, B);   // (8,16,8)

    if (avail >= splitBytes) {
        // tail region: split buffers now, scores/probs later (aliased)
        char* q = p;
        UST* xh  = (UST*)q; q += BSH * 2;
        UST* xl  = (UST*)q; q += BSH * 2;
        UST* wqh = (UST*)q; q += HH * 2;
        UST* wql = (UST*)q; q += HH * 2;
        UST* wkh = (UST*)q; q += HH * 2;
        UST* wkl = (UST*)q; q += HH * 2;
        UST* wvh = (UST*)q; q += HH * 2;

        split_kernel<<<2048, blk, 0, stream>>>(x, xh, xl, (int)(BSH / 4));
        split_kernel<<<256, blk, 0, stream>>>(Wq, wqh, wql, (int)(HH / 4));
        split_kernel<<<256, blk, 0, stream>>>(Wk, wkh, wkl, (int)(HH / 4));
        cvt_hi_kernel<<<256, blk, 0, stream>>>(Wv, wvh, (int)(HH / 4));

        gemm_bt<3, 0, 1, true><<<gproj, blk, 0, stream>>>(xh, xl, wqh, wql, bq, qh, ql, H, H, sXH, 0, sXH);
        gemm_bt<3, 0, 1, true><<<gproj, blk, 0, stream>>>(xh, xl, wkh, wkl, bk, kh, kl, H, H, sXH, 0, sXH);
        gemm_bt<1, 0, 2, true><<<gproj, blk, 0, stream>>>(xh, nullptr, wvh, nullptr, bv, vt, nullptr, H, S, sXH, 0, (long long)H * S);

        int g = (int)(avail / perB);
        if (g > 8) g = 8;
        if (g < 1) g = 1;
        while (8 % g) g--;
        float* scores = (float*)p;            // aliases split buffers (dead now)
        UST* probs = (UST*)(p + (size_t)g * S * S * 4);

        for (int b0 = 0; b0 < B; b0 += g) {
            dim3 gsc(S / 128, S / 128, g);
            gemm_bt<3, 0, 0, false><<<gsc, blk, 0, stream>>>(
                qh + (size_t)b0 * S * H, ql + (size_t)b0 * S * H,
                kh + (size_t)b0 * S * H, kl + (size_t)b0 * S * H, nullptr,
                scores, nullptr, H, S, sXH, sXH, (long long)S * S);

            softmax_bf16<<<g * S, blk, 0, stream>>>(scores, probs);

            dim3 gpv(H / 128, S / 128, g);
            gemm_bt<1, 0, 0, false><<<gpv, blk, 0, stream>>>(
                probs, nullptr, vt + (size_t)b0 * H * S, nullptr, nullptr,
                out + (size_t)b0 * S * H, nullptr, S, H,
                (long long)S * S, (long long)H * S, sXH);
        }
    } else {
        // tight-workspace fallback: in-kernel fp32 split + row-chunked scores
        gemm_bt<3, 1, 1, true><<<gproj, blk, 0, stream>>>(x, nullptr, Wq, nullptr, bq, qh, ql, H, H, sXH, 0, sXH);
        gemm_bt<3, 1, 1, true><<<gproj, blk, 0, stream>>>(x, nullptr, Wk, nullptr, bk, kh, kl, H, H, sXH, 0, sXH);
        gemm_bt<1, 1, 2, true><<<gproj, blk, 0, stream>>>(x, nullptr, Wv, nullptr, bv, vt, nullptr, H, S, sXH, 0, (long long)H * S);

        int rows = (int)(avail / ((size_t)S * 6 * 128)) * 128;
        if (rows < 128) rows = 128;
        if (rows > S) rows = S;
        float* scores = (float*)p;
        UST* probs = (UST*)(p + (size_t)rows * S * 4);

        for (int b = 0; b < B; b++) {
            for (int r0 = 0; r0 < S; r0 += rows) {
                int rc = S - r0 < rows ? S - r0 : rows;
                dim3 gsc(S / 128, rc / 128, 1);
                gemm_bt<3, 0, 0, false><<<gsc, blk, 0, stream>>>(
                    qh + (size_t)b * S * H + (size_t)r0 * H,
                    ql + (size_t)b * S * H + (size_t)r0 * H,
                    kh + (size_t)b * S * H, kl + (size_t)b * S * H, nullptr,
                    scores, nullptr, H, S, 0, 0, 0);

                softmax_bf16<<<rc, blk, 0, stream>>>(scores, probs);

                dim3 gpv(H / 128, rc / 128, 1);
                gemm_bt<1, 0, 0, false><<<gpv, blk, 0, stream>>>(
                    probs, nullptr, vt + (size_t)b * H * S, nullptr, nullptr,
                    out + (size_t)b * S * H + (size_t)r0 * H, nullptr, S, H,
                    0, 0, 0);
            }
        }
    }
}